// Round 4
// baseline (719.950 us; speedup 1.0000x reference)
//
#include <hip/hip_runtime.h>
#include <hip/hip_cooperative_groups.h>
#include <stdint.h>

#define HH 128
typedef unsigned long long ull;
typedef unsigned short u16;
namespace cg = cooperative_groups;

__device__ __forceinline__ ull shfl_up64(ull v, int d) {
  unsigned lo = (unsigned)__shfl_up((int)(unsigned)(v & 0xffffffffULL), d);
  unsigned hi = (unsigned)__shfl_up((int)(unsigned)(v >> 32), d);
  return ((ull)hi << 32) | (ull)lo;
}

// =============== cooperative graph-preprocessing mega-kernel ===============
struct GP {
  const int *z, *srcA, *dstA;
  int N, E, P, nbp;
  ull *cnt64; int *mark; int *pos;
  ull *locout, *partials;
  int *rowptr, *mlist, *minv, *plist, *Rm;
  int4 *pack; u16 *keyN;
  ull *csrk;
};

__global__ __launch_bounds__(256, 4) void k_graph(GP g) {
  cg::grid_group grid = cg::this_grid();
  __shared__ ull wsum[4];
  int t = threadIdx.x, b = blockIdx.x;
  int gid = b * 256 + t;
  int nthr = gridDim.x * 256;

  // P0: init
  for (int n = gid; n < g.N; n += nthr) {
    g.cnt64[n] = 0ULL;
    g.mark[n] = (g.z[n] <= 2) ? 1 : 0;
  }
  grid.sync();

  // P1: edge pass — one 64-bit atomic packs deg|cnt1|cnt2; slot pos from old value
  for (int e = gid; e < g.E; e += nthr) {
    int s = g.srcA[e], d = g.dstA[e];
    int zs = g.z[s];
    ull val = 1ULL | ((ull)(zs == 1) << 20) | ((ull)(zs == 2) << 40);
    ull old = atomicAdd(&g.cnt64[d], val);
    g.pos[e] = (int)(old & 0xFFFFF);
    if (g.z[d] <= 2) g.mark[s] = 1;
  }
  grid.sync();

  // P2: per-block scan of packed field deg|mark|(z==1)|(z==2), one elem/thread
  {
    int n = gid;
    ull v = 0;
    if (n < g.N) {
      int zz = g.z[n];
      v = (g.cnt64[n] & 0xFFFFFULL) | ((ull)g.mark[n] << 20)
        | ((ull)(zz == 1) << 40) | ((ull)(zz == 2) << 52);
    }
    int lane = t & 63, wid = t >> 6;
    ull vi = v;
    for (int d2 = 1; d2 < 64; d2 <<= 1) { ull o = shfl_up64(vi, d2); if (lane >= d2) vi += o; }
    if (lane == 63) wsum[wid] = vi;
    __syncthreads();
    ull woff = 0;
    for (int w2 = 0; w2 < wid; w2++) woff += wsum[w2];
    if (n < g.N) g.locout[n] = woff + vi - v;
    if (t == 255 && b < g.nbp) g.partials[b] = woff + vi;
  }
  grid.sync();

  // P3: block 0 scans the <=256 block partials
  if (b == 0) {
    ull v = (t < g.nbp) ? g.partials[t] : 0ULL;
    int lane = t & 63, wid = t >> 6;
    ull vi = v;
    for (int d2 = 1; d2 < 64; d2 <<= 1) { ull o = shfl_up64(vi, d2); if (lane >= d2) vi += o; }
    __syncthreads();   // wsum reuse safe: all block-0 threads past P2
    if (lane == 63) wsum[wid] = vi;
    __syncthreads();
    ull woff = 0;
    for (int w2 = 0; w2 < wid; w2++) woff += wsum[w2];
    if (t < g.nbp) g.partials[t] = woff + vi - v;
  }
  grid.sync();

  // P4: post — rowptr, mlist/minv, plist, pack, per-node key
  {
    int n = gid;
    if (n < g.N) {
      ull s = g.locout[n] + g.partials[n >> 8];
      int rp = (int)(s & 0xFFFFF);
      int mp = (int)((s >> 20) & 0xFFFFF);
      int r1 = (int)((s >> 40) & 0xFFF);
      int r2 = (int)(s >> 52);
      g.rowptr[n] = rp;
      int mk = g.mark[n];
      if (mk) { g.mlist[mp] = n; g.minv[n] = mp; }
      int zz = g.z[n];
      if (zz == 1) g.plist[r1] = n;
      else if (zz == 2) g.plist[g.P + r2] = n;
      ull cv = g.cnt64[n];
      int dd = (int)(cv & 0xFFFFF), c1 = (int)((cv >> 20) & 0xFFFFF), c2 = (int)((cv >> 40) & 0xFFFFF);
      g.pack[n] = make_int4(dd, c1, c2, zz);
      int wcls = (zz == 1) ? 1 : ((zz == 2) ? 2 : 0);
      u16 key;
      if (dd < 64 && c1 < 8 && c2 < 8) key = (u16)(dd | (c1 << 6) | (c2 << 9) | (wcls << 12));
      else key = 0x8000;
      g.keyN[n] = key;
      if (n == g.N - 1) *g.Rm = mp + mk;
    }
  }
  grid.sync();

  // P5: CSR fill — src index + precomputed key in one 8B word, no atomics
  for (int e = gid; e < g.E; e += nthr) {
    int d = g.dstA[e];
    int s = g.srcA[e];
    int slot = g.rowptr[d] + g.pos[e];
    g.csrk[slot] = (ull)(unsigned)s | ((ull)g.keyN[s] << 32);
  }
}

// =============== y-tables (1024 x1-variants @ layer-2 weights) ===============
// Also computes vecs in-block from raw weights; block 0 publishes vecs to global.
__global__ __launch_bounds__(256) void k_ytab(
    const float* __restrict__ zt, const float* __restrict__ Wl0,
    const float* __restrict__ Wr0, const float* __restrict__ Wl2,
    const float* __restrict__ Wr2, const float* __restrict__ bl0,
    const float* __restrict__ bl1, float* __restrict__ y_l,
    float* __restrict__ y_rb, float* __restrict__ vecs_g) {
  __shared__ float ztS[2][HH];
  __shared__ float vS[4][HH];
  __shared__ float xS[16][HH];
  int t = threadIdx.x;
  ztS[t >> 7][t & 127] = zt[t];
  __syncthreads();
#pragma unroll
  for (int rep = 0; rep < 2; rep++) {
    int idx = t + rep * 256;
    int m = idx >> 7, j = idx & 127;
    const float* W = (m < 2) ? Wl0 : Wr0;
    const float* zrow = ztS[m & 1];
    float acc = 0.f;
    for (int k = 0; k < HH; k++) acc = fmaf(zrow[k], W[j * HH + k], acc);
    vS[m][j] = acc;
  }
  __syncthreads();
  if (blockIdx.x == 0) {
    vecs_g[t] = vS[t >> 7][t & 127];
    vecs_g[256 + t] = vS[2 + (t >> 7)][t & 127];
  }
  int v0 = blockIdx.x * 16;
#pragma unroll
  for (int rep = 0; rep < 8; rep++) {
    int idx = t + rep * 256;
    int r = idx >> 7, j = idx & 127;
    int v = v0 + r;
    int d = v >> 4, cnt = (v >> 1) & 7, sel = v & 1;
    float invd = 1.0f / (float)max(d, 1);
    float u1 = (float)cnt * invd, u0 = (float)(d - cnt) * invd;
    xS[r][j] = fmaxf(fmaf(u0, vS[0][j], fmaf(u1, vS[1][j], bl0[j] + vS[2 + sel][j])), 0.f);
  }
  __syncthreads();
  int j = t & 127, rh = t >> 7;
  float al[8], ar[8];
#pragma unroll
  for (int q = 0; q < 8; q++) { al[q] = 0.f; ar[q] = 0.f; }
  for (int k = 0; k < HH; k++) {
    float wl = Wl2[j * HH + k], wr = Wr2[j * HH + k];
#pragma unroll
    for (int q = 0; q < 8; q++) {
      float x = xS[rh * 8 + q][k];
      al[q] = fmaf(x, wl, al[q]);
      ar[q] = fmaf(x, wr, ar[q]);
    }
  }
  float bb = bl1[j];
#pragma unroll
  for (int q = 0; q < 8; q++) {
    int v = v0 + rh * 8 + q;
    y_l[((size_t)v << 7) + j] = al[q];
    y_rb[((size_t)v << 7) + j] = ar[q] + bb;
  }
}

// ---- exact fallback (deg>=64 or cnt>=8): on-the-fly matvec, raw weights ----
__device__ __noinline__ float4 yrow_fb(const float* __restrict__ vecs,
    const float* __restrict__ bl0, const float* __restrict__ Wm,
    int j4, int d, int cnt, int sel) {
  float invd = 1.0f / (float)max(d, 1);
  float u1 = (float)cnt * invd, u0 = (float)(d - cnt) * invd;
  const float* Rv = vecs + (2 + sel) * HH;
  float4 acc = make_float4(0, 0, 0, 0);
  for (int k = 0; k < HH; k++) {
    float x = fmaxf(fmaf(u0, vecs[k], fmaf(u1, vecs[HH + k], bl0[k] + Rv[k])), 0.f);
    acc.x = fmaf(x, Wm[(j4 + 0) * HH + k], acc.x);
    acc.y = fmaf(x, Wm[(j4 + 1) * HH + k], acc.y);
    acc.z = fmaf(x, Wm[(j4 + 2) * HH + k], acc.z);
    acc.w = fmaf(x, Wm[(j4 + 3) * HH + k], acc.w);
  }
  return acc;
}

__device__ __forceinline__ float4 yl_fetch(ull cv, int ch, int chsel, int j4,
    const float* __restrict__ y_l, const int4* __restrict__ pack,
    const float* __restrict__ vecs, const float* __restrict__ bl0,
    const float* __restrict__ Wl2) {
  int key = (int)(cv >> 32);
  if (key & 0x8000) {
    int s = (int)(cv & 0xFFFFFFFFULL);
    int4 p = pack[s];
    int cc = ch ? p.z : p.y;
    int sel = (p.w == chsel) ? 1 : 0;
    return yrow_fb(vecs, bl0, Wl2, j4, p.x, cc, sel);
  }
  int cc = (key >> (6 + 3 * ch)) & 7;
  int sel = (((key >> 12) & 3) == chsel) ? 1 : 0;
  int row = ((key & 63) << 4) + (cc << 1) + sel;
  return *(const float4*)(y_l + ((size_t)row << 7) + j4);
}

// =============== layer-2: x2c[task] = relu(mean_s y_l[key(s)] + y_rb[key(n)]) ===============
__global__ __launch_bounds__(256) void k_agg2Y(const int4* __restrict__ pack,
    const ull* __restrict__ csrk, const float* __restrict__ y_l,
    const float* __restrict__ y_rb, const float* __restrict__ vecs,
    const float* __restrict__ bl0, const float* __restrict__ bl1,
    const float* __restrict__ Wl2, const float* __restrict__ Wr2,
    const int* __restrict__ rowptr, const int* __restrict__ mlist,
    const int* __restrict__ Rdev, float* __restrict__ x2c) {
  int gt = blockIdx.x * blockDim.x + threadIdx.x;
  int w = gt >> 6, lane = gt & 63;
  int nw = (gridDim.x * blockDim.x) >> 6;
  int T = *Rdev;
  int ch = lane >> 5, j4 = (lane & 31) * 4;
  int chsel = ch + 1;
  for (int task = w; task < T; task += nw) {
    int n = mlist[task];
    int4 pn = pack[n];
    int beg = rowptr[n], d = pn.x;
    float4 acc = make_float4(0, 0, 0, 0);
    int i = 0;
    for (; i + 4 <= d; i += 4) {
      ull c0 = csrk[beg + i], c1 = csrk[beg + i + 1];
      ull c2 = csrk[beg + i + 2], c3 = csrk[beg + i + 3];
      float4 v0 = yl_fetch(c0, ch, chsel, j4, y_l, pack, vecs, bl0, Wl2);
      float4 v1 = yl_fetch(c1, ch, chsel, j4, y_l, pack, vecs, bl0, Wl2);
      float4 v2 = yl_fetch(c2, ch, chsel, j4, y_l, pack, vecs, bl0, Wl2);
      float4 v3 = yl_fetch(c3, ch, chsel, j4, y_l, pack, vecs, bl0, Wl2);
      acc.x += v0.x + v1.x + v2.x + v3.x;
      acc.y += v0.y + v1.y + v2.y + v3.y;
      acc.z += v0.z + v1.z + v2.z + v3.z;
      acc.w += v0.w + v1.w + v2.w + v3.w;
    }
    for (; i < d; i++) {
      float4 v0 = yl_fetch(csrk[beg + i], ch, chsel, j4, y_l, pack, vecs, bl0, Wl2);
      acc.x += v0.x; acc.y += v0.y; acc.z += v0.z; acc.w += v0.w;
    }
    float inv = 1.0f / (float)max(d, 1);
    int ccn = ch ? pn.z : pn.y;
    int seln = (pn.w == chsel) ? 1 : 0;
    float4 yr;
    if (pn.x < 64 && ccn < 8) {
      yr = *(const float4*)(y_rb + ((size_t)(((pn.x << 3) + ccn) * 2 + seln) << 7) + j4);
    } else {
      yr = yrow_fb(vecs, bl0, Wr2, j4, pn.x, ccn, seln);
      yr.x += bl1[j4]; yr.y += bl1[j4 + 1]; yr.z += bl1[j4 + 2]; yr.w += bl1[j4 + 3];
    }
    float4 o;
    o.x = fmaxf(fmaf(acc.x, inv, yr.x), 0.f);
    o.y = fmaxf(fmaf(acc.y, inv, yr.y), 0.f);
    o.z = fmaxf(fmaf(acc.z, inv, yr.z), 0.f);
    o.w = fmaxf(fmaf(acc.w, inv, yr.w), 0.f);
    *(float4*)(x2c + (size_t)task * 256 + ch * HH + j4) = o;
  }
}

// =============== fused layer-3 aggregate + dual GEMM + W0 stage ===============
#define G3 8
__global__ __launch_bounds__(256) void k_aggL3F(const float* __restrict__ x2c,
    const ull* __restrict__ csrk, const int* __restrict__ rowptr,
    const int4* __restrict__ pack, const int* __restrict__ plist,
    const int* __restrict__ minv, const float* __restrict__ Wl3,
    const float* __restrict__ Wr3, const float* __restrict__ W0,
    const float* __restrict__ bl2, const float* __restrict__ b0,
    float* __restrict__ tmp0) {
  __shared__ float aS[G3][256];
  __shared__ float xS[G3][256];
  __shared__ float x3S[G3][256];
  int t = threadIdx.x;
  int i0 = blockIdx.x * G3;
  for (int g = 0; g < G3; g++) {
    int i = i0 + g;
    int n = plist[i];
    int beg = rowptr[n], d = pack[n].x;
    float acc = 0.f;
    int k = 0;
    for (; k + 4 <= d; k += 4) {
      int m0 = minv[(int)(csrk[beg + k] & 0xFFFFFFFFULL)];
      int m1 = minv[(int)(csrk[beg + k + 1] & 0xFFFFFFFFULL)];
      int m2 = minv[(int)(csrk[beg + k + 2] & 0xFFFFFFFFULL)];
      int m3 = minv[(int)(csrk[beg + k + 3] & 0xFFFFFFFFULL)];
      acc += x2c[(size_t)m0 * 256 + t] + x2c[(size_t)m1 * 256 + t]
           + x2c[(size_t)m2 * 256 + t] + x2c[(size_t)m3 * 256 + t];
    }
    for (; k < d; k++)
      acc += x2c[(size_t)minv[(int)(csrk[beg + k] & 0xFFFFFFFFULL)] * 256 + t];
    aS[g][t] = acc / (float)max(d, 1);
    xS[g][t] = x2c[(size_t)minv[n] * 256 + t];
  }
  __syncthreads();
  {
    int c = t >> 7, j = t & 127;
    float acc[G3];
#pragma unroll
    for (int g = 0; g < G3; g++) acc[g] = bl2[j];
    for (int k = 0; k < HH; k++) {
      float wl = Wl3[j * HH + k], wr = Wr3[j * HH + k];
#pragma unroll
      for (int g = 0; g < G3; g++)
        acc[g] = fmaf(aS[g][c * HH + k], wl, fmaf(xS[g][c * HH + k], wr, acc[g]));
    }
#pragma unroll
    for (int g = 0; g < G3; g++) x3S[g][t] = acc[g];
  }
  __syncthreads();
  {
    int c = t >> 7, j = t & 127;
    float acc[G3];
#pragma unroll
    for (int g = 0; g < G3; g++) acc[g] = b0[j];
    for (int k = 0; k < HH; k++) {
      float w0 = W0[j * HH + k];
#pragma unroll
      for (int g = 0; g < G3; g++) acc[g] = fmaf(x3S[g][c * HH + k], w0, acc[g]);
    }
#pragma unroll
    for (int g = 0; g < G3; g++)
      tmp0[(size_t)(2 * (i0 + g) + c) * HH + j] = fmaxf(acc[g], 0.f);
  }
}

// =============== pair product + final MLP ===============
__global__ __launch_bounds__(256) void k_finalP(const float* __restrict__ tmp0,
    const float* __restrict__ W1, const float* __restrict__ b1,
    const float* __restrict__ W2, const float* __restrict__ b2,
    int P, float* __restrict__ out) {
  __shared__ float pS[2][HH];
  __shared__ float wred[4];
  int t = threadIdx.x;
  int half = t >> 7, j = t & 127;
  int i = blockIdx.x * 2 + half;
  float hs = tmp0[(size_t)(2 * i) * HH + j] + tmp0[(size_t)(2 * i + 1) * HH + j];
  float hd = tmp0[(size_t)(2 * (i + P)) * HH + j] + tmp0[(size_t)(2 * (i + P) + 1) * HH + j];
  pS[half][j] = hs * hd;
  __syncthreads();
  float acc = b1[j];
#pragma unroll 8
  for (int k = 0; k < HH; k++) acc = fmaf(pS[half][k], W1[j * HH + k], acc);
  float v = fmaxf(acc, 0.f) * W2[j];
  for (int off = 32; off > 0; off >>= 1) v += __shfl_down(v, off);
  int wid = t >> 6, lane = t & 63;
  if (lane == 0) wred[wid] = v;
  __syncthreads();
  if (t == 0) out[i] = wred[0] + wred[1] + b2[0];
  else if (t == 128) out[i] = wred[2] + wred[3] + b2[0];
}

extern "C" void kernel_launch(void* const* d_in, const int* in_sizes, int n_in,
                              void* d_out, int out_size, void* d_ws, size_t ws_size,
                              hipStream_t stream) {
  const int* z = (const int*)d_in[0];
  const int* ei = (const int*)d_in[1];
  const float* z_table = (const float*)d_in[3];
  const float* conv_Wl = (const float*)d_in[4];
  const float* conv_bl = (const float*)d_in[5];
  const float* conv_Wr = (const float*)d_in[6];
  const float* W0 = (const float*)d_in[7];
  const float* b0 = (const float*)d_in[8];
  const float* W1 = (const float*)d_in[9];
  const float* b1 = (const float*)d_in[10];
  const float* W2 = (const float*)d_in[11];
  const float* b2 = (const float*)d_in[12];
  float* out = (float*)d_out;

  int N = in_sizes[0];
  int E = in_sizes[1] / 2;
  int P = out_size;
  int P2 = 2 * P;
  const int* srcA = ei;
  const int* dstA = ei + E;

  char* basep = (char*)d_ws;
  size_t off = 0;
  auto alloc = [&](size_t bytes) -> char* {
    off = (off + 255) & ~(size_t)255;
    char* pp = basep + off; off += bytes; return pp;
  };
  float* y_l   = (float*)alloc((size_t)1024 * HH * 4);
  float* y_rb  = (float*)alloc((size_t)1024 * HH * 4);
  float* vecs  = (float*)alloc((size_t)4 * HH * 4);
  float* x2c   = (float*)alloc((size_t)N * 256 * 4);
  float* tmp0  = (float*)alloc((size_t)2 * P2 * HH * 4);
  ull*   cnt64 = (ull*)alloc((size_t)N * 8);
  int*   mark  = (int*)alloc((size_t)N * 4);
  int*   pos   = (int*)alloc((size_t)E * 4);
  int*   rowptr= (int*)alloc((size_t)N * 4);
  int*   mlist = (int*)alloc((size_t)N * 4);
  int*   minv  = (int*)alloc((size_t)N * 4);
  int*   plist = (int*)alloc((size_t)P2 * 4);
  ull*   csrk  = (ull*)alloc((size_t)E * 8);
  ull*   locout= (ull*)alloc((size_t)N * 8);
  ull*   partials = (ull*)alloc(1024 * 8);
  int*   Rm_dev = (int*)alloc(256);
  u16*   keyN  = (u16*)alloc((size_t)N * 2);
  int4*  pack  = (int4*)alloc((size_t)N * 16);
  (void)ws_size; (void)n_in;

  GP gp;
  gp.z = z; gp.srcA = srcA; gp.dstA = dstA;
  gp.N = N; gp.E = E; gp.P = P; gp.nbp = (N + 255) / 256;
  gp.cnt64 = cnt64; gp.mark = mark; gp.pos = pos;
  gp.locout = locout; gp.partials = partials;
  gp.rowptr = rowptr; gp.mlist = mlist; gp.minv = minv; gp.plist = plist;
  gp.Rm = Rm_dev; gp.pack = pack; gp.keyN = keyN; gp.csrk = csrk;
  void* args[] = { &gp };
  hipLaunchCooperativeKernel((const void*)k_graph, dim3(1024), dim3(256), args, 0, stream);

  k_ytab<<<64, 256, 0, stream>>>(z_table, conv_Wl, conv_Wr,
                                 conv_Wl + HH * HH, conv_Wr + HH * HH,
                                 conv_bl, conv_bl + HH, y_l, y_rb, vecs);
  k_agg2Y<<<2048, 256, 0, stream>>>(pack, csrk, y_l, y_rb, vecs, conv_bl, conv_bl + HH,
                                    conv_Wl + HH * HH, conv_Wr + HH * HH,
                                    rowptr, mlist, Rm_dev, x2c);
  k_aggL3F<<<P2 / G3, 256, 0, stream>>>(x2c, csrk, rowptr, pack, plist, minv,
                                        conv_Wl + 2 * HH * HH, conv_Wr + 2 * HH * HH,
                                        W0, conv_bl + 2 * HH, b0, tmp0);
  k_finalP<<<P / 2, 256, 0, stream>>>(tmp0, W1, b1, W2, b2, P, out);
}

// Round 5
// 148.150 us; speedup vs baseline: 4.8596x; 4.8596x over previous
//
#include <hip/hip_runtime.h>
#include <stdint.h>

#define HH 128
typedef unsigned long long ull;
typedef unsigned short u16;

__device__ __forceinline__ ull shfl_up64(ull v, int d) {
  unsigned lo = (unsigned)__shfl_up((int)(unsigned)(v & 0xffffffffULL), d);
  unsigned hi = (unsigned)__shfl_up((int)(unsigned)(v >> 32), d);
  return ((ull)hi << 32) | (ull)lo;
}
__device__ __forceinline__ ull shfl_down64(ull v, int d) {
  unsigned lo = (unsigned)__shfl_down((int)(unsigned)(v & 0xffffffffULL), d);
  unsigned hi = (unsigned)__shfl_down((int)(unsigned)(v >> 32), d);
  return ((ull)hi << 32) | (ull)lo;
}

// =============== y-tables + init prologue (zero cnt64, seed mark) ===============
// 64 blocks; block b computes 16 table rows. Block 0 also publishes vecs.
__global__ __launch_bounds__(256) void k_ytab(
    const float* __restrict__ zt, const float* __restrict__ Wl0,
    const float* __restrict__ Wr0, const float* __restrict__ Wl2,
    const float* __restrict__ Wr2, const float* __restrict__ bl0,
    const float* __restrict__ bl1, float* __restrict__ y_l,
    float* __restrict__ y_rb, float* __restrict__ vecs_g,
    const int* __restrict__ z, int N, ull* __restrict__ cnt64,
    int* __restrict__ mark) {
  __shared__ float ztS[2][HH];
  __shared__ float vS[4][HH];
  __shared__ float xS[16][HH];
  int t = threadIdx.x;
  // init prologue: zero cnt64, seed mark (stream order protects k_edge)
  {
    int gid = blockIdx.x * 256 + t;
    int nthr = gridDim.x * 256;
    for (int n = gid; n < N; n += nthr) {
      cnt64[n] = 0ULL;
      mark[n] = (z[n] <= 2) ? 1 : 0;
    }
  }
  ztS[t >> 7][t & 127] = zt[t];
  __syncthreads();
#pragma unroll
  for (int rep = 0; rep < 2; rep++) {
    int idx = t + rep * 256;
    int m = idx >> 7, j = idx & 127;
    const float* W = (m < 2) ? Wl0 : Wr0;
    const float* zrow = ztS[m & 1];
    float acc = 0.f;
    for (int k = 0; k < HH; k++) acc = fmaf(zrow[k], W[j * HH + k], acc);
    vS[m][j] = acc;
  }
  __syncthreads();
  if (blockIdx.x == 0) {
    vecs_g[t] = vS[t >> 7][t & 127];
    vecs_g[256 + t] = vS[2 + (t >> 7)][t & 127];
  }
  int v0 = blockIdx.x * 16;
#pragma unroll
  for (int rep = 0; rep < 8; rep++) {
    int idx = t + rep * 256;
    int r = idx >> 7, j = idx & 127;
    int v = v0 + r;
    int d = v >> 4, cnt = (v >> 1) & 7, sel = v & 1;
    float invd = 1.0f / (float)max(d, 1);
    float u1 = (float)cnt * invd, u0 = (float)(d - cnt) * invd;
    xS[r][j] = fmaxf(fmaf(u0, vS[0][j], fmaf(u1, vS[1][j], bl0[j] + vS[2 + sel][j])), 0.f);
  }
  __syncthreads();
  int j = t & 127, rh = t >> 7;
  float al[8], ar[8];
#pragma unroll
  for (int q = 0; q < 8; q++) { al[q] = 0.f; ar[q] = 0.f; }
  for (int k = 0; k < HH; k++) {
    float wl = Wl2[j * HH + k], wr = Wr2[j * HH + k];
#pragma unroll
    for (int q = 0; q < 8; q++) {
      float x = xS[rh * 8 + q][k];
      al[q] = fmaf(x, wl, al[q]);
      ar[q] = fmaf(x, wr, ar[q]);
    }
  }
  float bb = bl1[j];
#pragma unroll
  for (int q = 0; q < 8; q++) {
    int v = v0 + rh * 8 + q;
    y_l[((size_t)v << 7) + j] = al[q];
    y_rb[((size_t)v << 7) + j] = ar[q] + bb;
  }
}

// =============== edge pass: packed atomic gives slot for free ===============
__global__ void k_edge(const int* __restrict__ z, const int* __restrict__ src,
                       const int* __restrict__ dst, int E,
                       ull* __restrict__ cnt64, int* __restrict__ mark,
                       int* __restrict__ pos) {
  int tid = blockIdx.x * blockDim.x + threadIdx.x;
  int stride = gridDim.x * blockDim.x;
  for (int e = tid; e < E; e += stride) {
    int s = src[e], d = dst[e];
    int zs = z[s];
    ull val = 1ULL | ((ull)(zs == 1) << 20) | ((ull)(zs == 2) << 40);
    ull old = atomicAdd(&cnt64[d], val);
    pos[e] = (int)(old & 0xFFFFF);
    if (z[d] <= 2) mark[s] = 1;
  }
}

// ---- packed 64-bit scan: deg(0..19) | mark(20..39) | z==1(40..51) | z==2(52..63) ----
__global__ void k_scan1(const ull* __restrict__ cnt64, const int* __restrict__ mark,
                        const int* __restrict__ z, int N,
                        ull* __restrict__ locout, ull* __restrict__ partials) {
  __shared__ ull wsum[4];
  int t = threadIdx.x, b = blockIdx.x;
  int base = b * 1024 + t * 4;
  ull l[4]; ull s = 0;
  for (int i = 0; i < 4; i++) {
    int idx = base + i; ull v = 0;
    if (idx < N) {
      int zz = z[idx];
      v = (cnt64[idx] & 0xFFFFFULL) | ((ull)mark[idx] << 20)
        | ((ull)(zz == 1) << 40) | ((ull)(zz == 2) << 52);
    }
    l[i] = s; s += v;
  }
  int lane = t & 63, wid = t >> 6;
  ull vi = s;
  for (int d2 = 1; d2 < 64; d2 <<= 1) { ull o = shfl_up64(vi, d2); if (lane >= d2) vi += o; }
  if (lane == 63) wsum[wid] = vi;
  __syncthreads();
  ull woff = 0;
  for (int w = 0; w < wid; w++) woff += wsum[w];
  ull thrbase = woff + vi - s;
  for (int i = 0; i < 4; i++) {
    int idx = base + i;
    if (idx < N) locout[idx] = thrbase + l[i];
  }
  if (t == 255) partials[b] = woff + vi;
}

// ---- consume scan: rowptr, mlist/minv, plist, pack, keyN ----
__global__ __launch_bounds__(256) void k_post(const ull* __restrict__ locout, const ull* __restrict__ partials,
                       const int* __restrict__ z, const int* __restrict__ mark,
                       const ull* __restrict__ cnt64,
                       int N, int P, int* __restrict__ rowptr, int* __restrict__ mlist,
                       int* __restrict__ minv, int* __restrict__ plist,
                       int* __restrict__ Rm, int4* __restrict__ pack,
                       u16* __restrict__ keyN) {
  __shared__ ull base_s;
  int t = threadIdx.x;
  if (t < 64) {
    int need = blockIdx.x >> 2;   // chunk index = (block*256)>>10
    ull v = (t < need) ? partials[t] : 0ULL;
    for (int o = 32; o > 0; o >>= 1) v += shfl_down64(v, o);
    if (t == 0) base_s = v;
  }
  __syncthreads();
  int n = blockIdx.x * 256 + t;
  if (n >= N) return;
  ull s = locout[n] + base_s;
  int rp = (int)(s & 0xFFFFF);
  int mp = (int)((s >> 20) & 0xFFFFF);
  int r1 = (int)((s >> 40) & 0xFFF);
  int r2 = (int)(s >> 52);
  rowptr[n] = rp;
  int mk = mark[n];
  if (mk) { mlist[mp] = n; minv[n] = mp; }
  int zz = z[n];
  if (zz == 1) plist[r1] = n;
  else if (zz == 2) plist[P + r2] = n;
  ull cv = cnt64[n];
  int dd = (int)(cv & 0xFFFFF), c1 = (int)((cv >> 20) & 0xFFFFF), c2 = (int)((cv >> 40) & 0xFFFFF);
  pack[n] = make_int4(dd, c1, c2, zz);
  int wcls = (zz == 1) ? 1 : ((zz == 2) ? 2 : 0);
  u16 key;
  if (dd < 64 && c1 < 8 && c2 < 8) key = (u16)(dd | (c1 << 6) | (c2 << 9) | (wcls << 12));
  else key = 0x8000;
  keyN[n] = key;
  if (n == N - 1) *Rm = mp + mk;
}

// ---- CSR fill: pure scatter (no atomics), embeds node key ----
__global__ void k_csrk(const int* __restrict__ src, const int* __restrict__ dst, int E,
                       const int* __restrict__ rowptr, const int* __restrict__ pos,
                       const u16* __restrict__ keyN, ull* __restrict__ csrk) {
  int e = blockIdx.x * blockDim.x + threadIdx.x;
  if (e >= E) return;
  int d = dst[e], s = src[e];
  csrk[rowptr[d] + pos[e]] = (ull)(unsigned)s | ((ull)keyN[s] << 32);
}

// ---- exact fallback (deg>=64 or cnt>=8): on-the-fly matvec, raw weights ----
__device__ __noinline__ float4 yrow_fb(const float* __restrict__ vecs,
    const float* __restrict__ bl0, const float* __restrict__ Wm,
    int j4, int d, int cnt, int sel) {
  float invd = 1.0f / (float)max(d, 1);
  float u1 = (float)cnt * invd, u0 = (float)(d - cnt) * invd;
  const float* Rv = vecs + (2 + sel) * HH;
  float4 acc = make_float4(0, 0, 0, 0);
  for (int k = 0; k < HH; k++) {
    float x = fmaxf(fmaf(u0, vecs[k], fmaf(u1, vecs[HH + k], bl0[k] + Rv[k])), 0.f);
    acc.x = fmaf(x, Wm[(j4 + 0) * HH + k], acc.x);
    acc.y = fmaf(x, Wm[(j4 + 1) * HH + k], acc.y);
    acc.z = fmaf(x, Wm[(j4 + 2) * HH + k], acc.z);
    acc.w = fmaf(x, Wm[(j4 + 3) * HH + k], acc.w);
  }
  return acc;
}

__device__ __forceinline__ float4 yl_fetch(ull cv, int ch, int chsel, int j4,
    const float* __restrict__ y_l, const int4* __restrict__ pack,
    const float* __restrict__ vecs, const float* __restrict__ bl0,
    const float* __restrict__ Wl2) {
  int key = (int)(cv >> 32);
  if (key & 0x8000) {
    int s = (int)(cv & 0xFFFFFFFFULL);
    int4 p = pack[s];
    int cc = ch ? p.z : p.y;
    int sel = (p.w == chsel) ? 1 : 0;
    return yrow_fb(vecs, bl0, Wl2, j4, p.x, cc, sel);
  }
  int cc = (key >> (6 + 3 * ch)) & 7;
  int sel = (((key >> 12) & 3) == chsel) ? 1 : 0;
  int row = ((key & 63) << 4) + (cc << 1) + sel;
  return *(const float4*)(y_l + ((size_t)row << 7) + j4);
}

// =============== layer-2: x2c[task] = relu(mean_s y_l[key(s)] + y_rb[key(n)]) ===============
__global__ __launch_bounds__(256) void k_agg2Y(const int4* __restrict__ pack,
    const ull* __restrict__ csrk, const float* __restrict__ y_l,
    const float* __restrict__ y_rb, const float* __restrict__ vecs,
    const float* __restrict__ bl0, const float* __restrict__ bl1,
    const float* __restrict__ Wl2, const float* __restrict__ Wr2,
    const int* __restrict__ rowptr, const int* __restrict__ mlist,
    const int* __restrict__ Rdev, float* __restrict__ x2c) {
  int gt = blockIdx.x * blockDim.x + threadIdx.x;
  int w = gt >> 6, lane = gt & 63;
  int nw = (gridDim.x * blockDim.x) >> 6;
  int T = *Rdev;
  int ch = lane >> 5, j4 = (lane & 31) * 4;
  int chsel = ch + 1;
  for (int task = w; task < T; task += nw) {
    int n = mlist[task];
    int4 pn = pack[n];
    int beg = rowptr[n], d = pn.x;
    float4 acc = make_float4(0, 0, 0, 0);
    int i = 0;
    for (; i + 4 <= d; i += 4) {
      ull c0 = csrk[beg + i], c1 = csrk[beg + i + 1];
      ull c2 = csrk[beg + i + 2], c3 = csrk[beg + i + 3];
      float4 v0 = yl_fetch(c0, ch, chsel, j4, y_l, pack, vecs, bl0, Wl2);
      float4 v1 = yl_fetch(c1, ch, chsel, j4, y_l, pack, vecs, bl0, Wl2);
      float4 v2 = yl_fetch(c2, ch, chsel, j4, y_l, pack, vecs, bl0, Wl2);
      float4 v3 = yl_fetch(c3, ch, chsel, j4, y_l, pack, vecs, bl0, Wl2);
      acc.x += v0.x + v1.x + v2.x + v3.x;
      acc.y += v0.y + v1.y + v2.y + v3.y;
      acc.z += v0.z + v1.z + v2.z + v3.z;
      acc.w += v0.w + v1.w + v2.w + v3.w;
    }
    for (; i < d; i++) {
      float4 v0 = yl_fetch(csrk[beg + i], ch, chsel, j4, y_l, pack, vecs, bl0, Wl2);
      acc.x += v0.x; acc.y += v0.y; acc.z += v0.z; acc.w += v0.w;
    }
    float inv = 1.0f / (float)max(d, 1);
    int ccn = ch ? pn.z : pn.y;
    int seln = (pn.w == chsel) ? 1 : 0;
    float4 yr;
    if (pn.x < 64 && ccn < 8) {
      yr = *(const float4*)(y_rb + ((size_t)(((pn.x << 3) + ccn) * 2 + seln) << 7) + j4);
    } else {
      yr = yrow_fb(vecs, bl0, Wr2, j4, pn.x, ccn, seln);
      yr.x += bl1[j4]; yr.y += bl1[j4 + 1]; yr.z += bl1[j4 + 2]; yr.w += bl1[j4 + 3];
    }
    float4 o;
    o.x = fmaxf(fmaf(acc.x, inv, yr.x), 0.f);
    o.y = fmaxf(fmaf(acc.y, inv, yr.y), 0.f);
    o.z = fmaxf(fmaf(acc.z, inv, yr.z), 0.f);
    o.w = fmaxf(fmaf(acc.w, inv, yr.w), 0.f);
    *(float4*)(x2c + (size_t)task * 256 + ch * HH + j4) = o;
  }
}

// =============== fused layer-3 aggregate + dual GEMM + W0 stage ===============
#define G3 8
__global__ __launch_bounds__(256) void k_aggL3F(const float* __restrict__ x2c,
    const ull* __restrict__ csrk, const int* __restrict__ rowptr,
    const int4* __restrict__ pack, const int* __restrict__ plist,
    const int* __restrict__ minv, const float* __restrict__ Wl3,
    const float* __restrict__ Wr3, const float* __restrict__ W0,
    const float* __restrict__ bl2, const float* __restrict__ b0,
    float* __restrict__ tmp0) {
  __shared__ float aS[G3][256];
  __shared__ float xS[G3][256];
  __shared__ float x3S[G3][256];
  int t = threadIdx.x;
  int i0 = blockIdx.x * G3;
  for (int g = 0; g < G3; g++) {
    int i = i0 + g;
    int n = plist[i];
    int beg = rowptr[n], d = pack[n].x;
    float acc = 0.f;
    int k = 0;
    for (; k + 4 <= d; k += 4) {
      int m0 = minv[(int)(csrk[beg + k] & 0xFFFFFFFFULL)];
      int m1 = minv[(int)(csrk[beg + k + 1] & 0xFFFFFFFFULL)];
      int m2 = minv[(int)(csrk[beg + k + 2] & 0xFFFFFFFFULL)];
      int m3 = minv[(int)(csrk[beg + k + 3] & 0xFFFFFFFFULL)];
      acc += x2c[(size_t)m0 * 256 + t] + x2c[(size_t)m1 * 256 + t]
           + x2c[(size_t)m2 * 256 + t] + x2c[(size_t)m3 * 256 + t];
    }
    for (; k < d; k++)
      acc += x2c[(size_t)minv[(int)(csrk[beg + k] & 0xFFFFFFFFULL)] * 256 + t];
    aS[g][t] = acc / (float)max(d, 1);
    xS[g][t] = x2c[(size_t)minv[n] * 256 + t];
  }
  __syncthreads();
  {
    int c = t >> 7, j = t & 127;
    float acc[G3];
#pragma unroll
    for (int g = 0; g < G3; g++) acc[g] = bl2[j];
    for (int k = 0; k < HH; k++) {
      float wl = Wl3[j * HH + k], wr = Wr3[j * HH + k];
#pragma unroll
      for (int g = 0; g < G3; g++)
        acc[g] = fmaf(aS[g][c * HH + k], wl, fmaf(xS[g][c * HH + k], wr, acc[g]));
    }
#pragma unroll
    for (int g = 0; g < G3; g++) x3S[g][t] = acc[g];
  }
  __syncthreads();
  {
    int c = t >> 7, j = t & 127;
    float acc[G3];
#pragma unroll
    for (int g = 0; g < G3; g++) acc[g] = b0[j];
    for (int k = 0; k < HH; k++) {
      float w0 = W0[j * HH + k];
#pragma unroll
      for (int g = 0; g < G3; g++) acc[g] = fmaf(x3S[g][c * HH + k], w0, acc[g]);
    }
#pragma unroll
    for (int g = 0; g < G3; g++)
      tmp0[(size_t)(2 * (i0 + g) + c) * HH + j] = fmaxf(acc[g], 0.f);
  }
}

// =============== pair product + final MLP ===============
__global__ __launch_bounds__(256) void k_finalP(const float* __restrict__ tmp0,
    const float* __restrict__ W1, const float* __restrict__ b1,
    const float* __restrict__ W2, const float* __restrict__ b2,
    int P, float* __restrict__ out) {
  __shared__ float pS[2][HH];
  __shared__ float wred[4];
  int t = threadIdx.x;
  int half = t >> 7, j = t & 127;
  int i = blockIdx.x * 2 + half;
  float hs = tmp0[(size_t)(2 * i) * HH + j] + tmp0[(size_t)(2 * i + 1) * HH + j];
  float hd = tmp0[(size_t)(2 * (i + P)) * HH + j] + tmp0[(size_t)(2 * (i + P) + 1) * HH + j];
  pS[half][j] = hs * hd;
  __syncthreads();
  float acc = b1[j];
#pragma unroll 8
  for (int k = 0; k < HH; k++) acc = fmaf(pS[half][k], W1[j * HH + k], acc);
  float v = fmaxf(acc, 0.f) * W2[j];
  for (int off = 32; off > 0; off >>= 1) v += __shfl_down(v, off);
  int wid = t >> 6, lane = t & 63;
  if (lane == 0) wred[wid] = v;
  __syncthreads();
  if (t == 0) out[i] = wred[0] + wred[1] + b2[0];
  else if (t == 128) out[i] = wred[2] + wred[3] + b2[0];
}

extern "C" void kernel_launch(void* const* d_in, const int* in_sizes, int n_in,
                              void* d_out, int out_size, void* d_ws, size_t ws_size,
                              hipStream_t stream) {
  const int* z = (const int*)d_in[0];
  const int* ei = (const int*)d_in[1];
  const float* z_table = (const float*)d_in[3];
  const float* conv_Wl = (const float*)d_in[4];
  const float* conv_bl = (const float*)d_in[5];
  const float* conv_Wr = (const float*)d_in[6];
  const float* W0 = (const float*)d_in[7];
  const float* b0 = (const float*)d_in[8];
  const float* W1 = (const float*)d_in[9];
  const float* b1 = (const float*)d_in[10];
  const float* W2 = (const float*)d_in[11];
  const float* b2 = (const float*)d_in[12];
  float* out = (float*)d_out;

  int N = in_sizes[0];
  int E = in_sizes[1] / 2;
  int P = out_size;
  int P2 = 2 * P;
  const int* srcA = ei;
  const int* dstA = ei + E;

  char* basep = (char*)d_ws;
  size_t off = 0;
  auto alloc = [&](size_t bytes) -> char* {
    off = (off + 255) & ~(size_t)255;
    char* pp = basep + off; off += bytes; return pp;
  };
  float* y_l   = (float*)alloc((size_t)1024 * HH * 4);
  float* y_rb  = (float*)alloc((size_t)1024 * HH * 4);
  float* vecs  = (float*)alloc((size_t)4 * HH * 4);
  float* x2c   = (float*)alloc((size_t)N * 256 * 4);
  float* tmp0  = (float*)alloc((size_t)2 * P2 * HH * 4);
  ull*   cnt64 = (ull*)alloc((size_t)N * 8);
  int*   mark  = (int*)alloc((size_t)N * 4);
  int*   pos   = (int*)alloc((size_t)E * 4);
  int*   rowptr= (int*)alloc((size_t)N * 4);
  int*   mlist = (int*)alloc((size_t)N * 4);
  int*   minv  = (int*)alloc((size_t)N * 4);
  int*   plist = (int*)alloc((size_t)P2 * 4);
  ull*   csrk  = (ull*)alloc((size_t)E * 8);
  ull*   locout= (ull*)alloc((size_t)N * 8);
  ull*   partials = (ull*)alloc(256 * 8);
  int*   Rm_dev = (int*)alloc(256);
  u16*   keyN  = (u16*)alloc((size_t)N * 2);
  int4*  pack  = (int4*)alloc((size_t)N * 16);
  (void)ws_size; (void)n_in;

  k_ytab<<<64, 256, 0, stream>>>(z_table, conv_Wl, conv_Wr,
                                 conv_Wl + HH * HH, conv_Wr + HH * HH,
                                 conv_bl, conv_bl + HH, y_l, y_rb, vecs,
                                 z, N, cnt64, mark);
  k_edge<<<1024, 256, 0, stream>>>(z, srcA, dstA, E, cnt64, mark, pos);
  int nb = (N + 1023) / 1024;
  k_scan1<<<nb, 256, 0, stream>>>(cnt64, mark, z, N, locout, partials);
  k_post<<<(N + 255) / 256, 256, 0, stream>>>(locout, partials, z, mark, cnt64, N, P,
                                              rowptr, mlist, minv, plist, Rm_dev, pack, keyN);
  k_csrk<<<(E + 255) / 256, 256, 0, stream>>>(srcA, dstA, E, rowptr, pos, keyN, csrk);
  k_agg2Y<<<2048, 256, 0, stream>>>(pack, csrk, y_l, y_rb, vecs, conv_bl, conv_bl + HH,
                                    conv_Wl + HH * HH, conv_Wr + HH * HH,
                                    rowptr, mlist, Rm_dev, x2c);
  k_aggL3F<<<P2 / G3, 256, 0, stream>>>(x2c, csrk, rowptr, pack, plist, minv,
                                        conv_Wl + 2 * HH * HH, conv_Wr + 2 * HH * HH,
                                        W0, conv_bl + 2 * HH, b0, tmp0);
  k_finalP<<<P / 2, 256, 0, stream>>>(tmp0, W1, b1, W2, b2, P, out);
}

// Round 6
// 132.697 us; speedup vs baseline: 5.4255x; 1.1164x over previous
//
#include <hip/hip_runtime.h>
#include <stdint.h>

#define HH 128
typedef unsigned long long ull;
typedef unsigned short u16;

__device__ __forceinline__ ull shfl_up64(ull v, int d) {
  unsigned lo = (unsigned)__shfl_up((int)(unsigned)(v & 0xffffffffULL), d);
  unsigned hi = (unsigned)__shfl_up((int)(unsigned)(v >> 32), d);
  return ((ull)hi << 32) | (ull)lo;
}
__device__ __forceinline__ ull shfl_down64(ull v, int d) {
  unsigned lo = (unsigned)__shfl_down((int)(unsigned)(v & 0xffffffffULL), d);
  unsigned hi = (unsigned)__shfl_down((int)(unsigned)(v >> 32), d);
  return ((ull)hi << 32) | (ull)lo;
}

// =============== y-tables + init prologue (zero cnt64, seed mark) ===============
__global__ __launch_bounds__(256) void k_ytab(
    const float* __restrict__ zt, const float* __restrict__ Wl0,
    const float* __restrict__ Wr0, const float* __restrict__ Wl2,
    const float* __restrict__ Wr2, const float* __restrict__ bl0,
    const float* __restrict__ bl1, float* __restrict__ y_l,
    float* __restrict__ y_rb, float* __restrict__ vecs_g,
    const int* __restrict__ z, int N, ull* __restrict__ cnt64,
    int* __restrict__ mark) {
  __shared__ float ztS[2][HH];
  __shared__ float vS[4][HH];
  __shared__ float xS[16][HH];
  int t = threadIdx.x;
  {
    int gid = blockIdx.x * 256 + t;
    int nthr = gridDim.x * 256;
    for (int n = gid; n < N; n += nthr) {
      cnt64[n] = 0ULL;
      mark[n] = (z[n] <= 2) ? 1 : 0;
    }
  }
  ztS[t >> 7][t & 127] = zt[t];
  __syncthreads();
#pragma unroll
  for (int rep = 0; rep < 2; rep++) {
    int idx = t + rep * 256;
    int m = idx >> 7, j = idx & 127;
    const float* W = (m < 2) ? Wl0 : Wr0;
    const float* zrow = ztS[m & 1];
    float acc = 0.f;
    for (int k = 0; k < HH; k++) acc = fmaf(zrow[k], W[j * HH + k], acc);
    vS[m][j] = acc;
  }
  __syncthreads();
  if (blockIdx.x == 0) {
    vecs_g[t] = vS[t >> 7][t & 127];
    vecs_g[256 + t] = vS[2 + (t >> 7)][t & 127];
  }
  int v0 = blockIdx.x * 16;
#pragma unroll
  for (int rep = 0; rep < 8; rep++) {
    int idx = t + rep * 256;
    int r = idx >> 7, j = idx & 127;
    int v = v0 + r;
    int d = v >> 4, cnt = (v >> 1) & 7, sel = v & 1;
    float invd = 1.0f / (float)max(d, 1);
    float u1 = (float)cnt * invd, u0 = (float)(d - cnt) * invd;
    xS[r][j] = fmaxf(fmaf(u0, vS[0][j], fmaf(u1, vS[1][j], bl0[j] + vS[2 + sel][j])), 0.f);
  }
  __syncthreads();
  int j = t & 127, rh = t >> 7;
  float al[8], ar[8];
#pragma unroll
  for (int q = 0; q < 8; q++) { al[q] = 0.f; ar[q] = 0.f; }
  for (int k = 0; k < HH; k++) {
    float wl = Wl2[j * HH + k], wr = Wr2[j * HH + k];
#pragma unroll
    for (int q = 0; q < 8; q++) {
      float x = xS[rh * 8 + q][k];
      al[q] = fmaf(x, wl, al[q]);
      ar[q] = fmaf(x, wr, ar[q]);
    }
  }
  float bb = bl1[j];
#pragma unroll
  for (int q = 0; q < 8; q++) {
    int v = v0 + rh * 8 + q;
    y_l[((size_t)v << 7) + j] = al[q];
    y_rb[((size_t)v << 7) + j] = ar[q] + bb;
  }
}

// =============== edge pass: packed atomic gives slot for free ===============
__global__ void k_edge(const int* __restrict__ z, const int* __restrict__ src,
                       const int* __restrict__ dst, int E,
                       ull* __restrict__ cnt64, int* __restrict__ mark,
                       int* __restrict__ pos) {
  int tid = blockIdx.x * blockDim.x + threadIdx.x;
  int stride = gridDim.x * blockDim.x;
  for (int e = tid; e < E; e += stride) {
    int s = src[e], d = dst[e];
    int zs = z[s];
    ull val = 1ULL | ((ull)(zs == 1) << 20) | ((ull)(zs == 2) << 40);
    ull old = atomicAdd(&cnt64[d], val);
    pos[e] = (int)(old & 0xFFFFF);
    if (z[d] <= 2) mark[s] = 1;
  }
}

// ---- packed 64-bit scan: deg(0..19) | mark(20..39) | z==1(40..51) | z==2(52..63) ----
__global__ void k_scan1(const ull* __restrict__ cnt64, const int* __restrict__ mark,
                        const int* __restrict__ z, int N,
                        ull* __restrict__ locout, ull* __restrict__ partials) {
  __shared__ ull wsum[4];
  int t = threadIdx.x, b = blockIdx.x;
  int base = b * 1024 + t * 4;
  ull l[4]; ull s = 0;
  for (int i = 0; i < 4; i++) {
    int idx = base + i; ull v = 0;
    if (idx < N) {
      int zz = z[idx];
      v = (cnt64[idx] & 0xFFFFFULL) | ((ull)mark[idx] << 20)
        | ((ull)(zz == 1) << 40) | ((ull)(zz == 2) << 52);
    }
    l[i] = s; s += v;
  }
  int lane = t & 63, wid = t >> 6;
  ull vi = s;
  for (int d2 = 1; d2 < 64; d2 <<= 1) { ull o = shfl_up64(vi, d2); if (lane >= d2) vi += o; }
  if (lane == 63) wsum[wid] = vi;
  __syncthreads();
  ull woff = 0;
  for (int w = 0; w < wid; w++) woff += wsum[w];
  ull thrbase = woff + vi - s;
  for (int i = 0; i < 4; i++) {
    int idx = base + i;
    if (idx < N) locout[idx] = thrbase + l[i];
  }
  if (t == 255) partials[b] = woff + vi;
}

// ---- consume scan: rowptr, mlist/minv, plist, pack, keyN ----
__global__ __launch_bounds__(256) void k_post(const ull* __restrict__ locout, const ull* __restrict__ partials,
                       const int* __restrict__ z, const int* __restrict__ mark,
                       const ull* __restrict__ cnt64,
                       int N, int P, int* __restrict__ rowptr, int* __restrict__ mlist,
                       int* __restrict__ minv, int* __restrict__ plist,
                       int* __restrict__ Rm, int4* __restrict__ pack,
                       u16* __restrict__ keyN) {
  __shared__ ull base_s;
  int t = threadIdx.x;
  if (t < 64) {
    int need = blockIdx.x >> 2;
    ull v = (t < need) ? partials[t] : 0ULL;
    for (int o = 32; o > 0; o >>= 1) v += shfl_down64(v, o);
    if (t == 0) base_s = v;
  }
  __syncthreads();
  int n = blockIdx.x * 256 + t;
  if (n >= N) return;
  ull s = locout[n] + base_s;
  int rp = (int)(s & 0xFFFFF);
  int mp = (int)((s >> 20) & 0xFFFFF);
  int r1 = (int)((s >> 40) & 0xFFF);
  int r2 = (int)(s >> 52);
  rowptr[n] = rp;
  int mk = mark[n];
  if (mk) { mlist[mp] = n; minv[n] = mp; }
  int zz = z[n];
  if (zz == 1) plist[r1] = n;
  else if (zz == 2) plist[P + r2] = n;
  ull cv = cnt64[n];
  int dd = (int)(cv & 0xFFFFF), c1 = (int)((cv >> 20) & 0xFFFFF), c2 = (int)((cv >> 40) & 0xFFFFF);
  pack[n] = make_int4(dd, c1, c2, zz);
  int wcls = (zz == 1) ? 1 : ((zz == 2) ? 2 : 0);
  u16 key;
  if (dd < 64 && c1 < 8 && c2 < 8) key = (u16)(dd | (c1 << 6) | (c2 << 9) | (wcls << 12));
  else key = 0x8000;
  keyN[n] = key;
  if (n == N - 1) *Rm = mp + mk;
}

// ---- CSR fill: pure scatter (no atomics), embeds node key ----
__global__ void k_csrk(const int* __restrict__ src, const int* __restrict__ dst, int E,
                       const int* __restrict__ rowptr, const int* __restrict__ pos,
                       const u16* __restrict__ keyN, ull* __restrict__ csrk) {
  int e = blockIdx.x * blockDim.x + threadIdx.x;
  if (e >= E) return;
  int d = dst[e], s = src[e];
  csrk[rowptr[d] + pos[e]] = (ull)(unsigned)s | ((ull)keyN[s] << 32);
}

// ---- exact fallback (deg>=64 or cnt>=8): on-the-fly matvec, raw weights ----
__device__ __noinline__ float4 yrow_fb(const float* __restrict__ vecs,
    const float* __restrict__ bl0, const float* __restrict__ Wm,
    int j4, int d, int cnt, int sel) {
  float invd = 1.0f / (float)max(d, 1);
  float u1 = (float)cnt * invd, u0 = (float)(d - cnt) * invd;
  const float* Rv = vecs + (2 + sel) * HH;
  float4 acc = make_float4(0, 0, 0, 0);
  for (int k = 0; k < HH; k++) {
    float x = fmaxf(fmaf(u0, vecs[k], fmaf(u1, vecs[HH + k], bl0[k] + Rv[k])), 0.f);
    acc.x = fmaf(x, Wm[(j4 + 0) * HH + k], acc.x);
    acc.y = fmaf(x, Wm[(j4 + 1) * HH + k], acc.y);
    acc.z = fmaf(x, Wm[(j4 + 2) * HH + k], acc.z);
    acc.w = fmaf(x, Wm[(j4 + 3) * HH + k], acc.w);
  }
  return acc;
}

__device__ __forceinline__ float4 yl_fetch(ull cv, int ch, int chsel, int j4,
    const float* __restrict__ y_l, const int4* __restrict__ pack,
    const float* __restrict__ vecs, const float* __restrict__ bl0,
    const float* __restrict__ Wl2) {
  int key = (int)(cv >> 32);
  if (key & 0x8000) {
    int s = (int)(cv & 0xFFFFFFFFULL);
    int4 p = pack[s];
    int cc = ch ? p.z : p.y;
    int sel = (p.w == chsel) ? 1 : 0;
    return yrow_fb(vecs, bl0, Wl2, j4, p.x, cc, sel);
  }
  int cc = (key >> (6 + 3 * ch)) & 7;
  int sel = (((key >> 12) & 3) == chsel) ? 1 : 0;
  int row = ((key & 63) << 4) + (cc << 1) + sel;
  return *(const float4*)(y_l + ((size_t)row << 7) + j4);
}

// =============== layer-2: x2c[task] = relu(mean_s y_l[key(s)] + y_rb[key(n)]) ===============
__global__ __launch_bounds__(256) void k_agg2Y(const int4* __restrict__ pack,
    const ull* __restrict__ csrk, const float* __restrict__ y_l,
    const float* __restrict__ y_rb, const float* __restrict__ vecs,
    const float* __restrict__ bl0, const float* __restrict__ bl1,
    const float* __restrict__ Wl2, const float* __restrict__ Wr2,
    const int* __restrict__ rowptr, const int* __restrict__ mlist,
    const int* __restrict__ Rdev, float* __restrict__ x2c) {
  int gt = blockIdx.x * blockDim.x + threadIdx.x;
  int w = gt >> 6, lane = gt & 63;
  int nw = (gridDim.x * blockDim.x) >> 6;
  int T = *Rdev;
  int ch = lane >> 5, j4 = (lane & 31) * 4;
  int chsel = ch + 1;
  for (int task = w; task < T; task += nw) {
    int n = mlist[task];
    int4 pn = pack[n];
    int beg = rowptr[n], d = pn.x;
    float4 acc = make_float4(0, 0, 0, 0);
    int i = 0;
    for (; i + 4 <= d; i += 4) {
      ull c0 = csrk[beg + i], c1 = csrk[beg + i + 1];
      ull c2 = csrk[beg + i + 2], c3 = csrk[beg + i + 3];
      float4 v0 = yl_fetch(c0, ch, chsel, j4, y_l, pack, vecs, bl0, Wl2);
      float4 v1 = yl_fetch(c1, ch, chsel, j4, y_l, pack, vecs, bl0, Wl2);
      float4 v2 = yl_fetch(c2, ch, chsel, j4, y_l, pack, vecs, bl0, Wl2);
      float4 v3 = yl_fetch(c3, ch, chsel, j4, y_l, pack, vecs, bl0, Wl2);
      acc.x += v0.x + v1.x + v2.x + v3.x;
      acc.y += v0.y + v1.y + v2.y + v3.y;
      acc.z += v0.z + v1.z + v2.z + v3.z;
      acc.w += v0.w + v1.w + v2.w + v3.w;
    }
    for (; i < d; i++) {
      float4 v0 = yl_fetch(csrk[beg + i], ch, chsel, j4, y_l, pack, vecs, bl0, Wl2);
      acc.x += v0.x; acc.y += v0.y; acc.z += v0.z; acc.w += v0.w;
    }
    float inv = 1.0f / (float)max(d, 1);
    int ccn = ch ? pn.z : pn.y;
    int seln = (pn.w == chsel) ? 1 : 0;
    float4 yr;
    if (pn.x < 64 && ccn < 8) {
      yr = *(const float4*)(y_rb + ((size_t)(((pn.x << 3) + ccn) * 2 + seln) << 7) + j4);
    } else {
      yr = yrow_fb(vecs, bl0, Wr2, j4, pn.x, ccn, seln);
      yr.x += bl1[j4]; yr.y += bl1[j4 + 1]; yr.z += bl1[j4 + 2]; yr.w += bl1[j4 + 3];
    }
    float4 o;
    o.x = fmaxf(fmaf(acc.x, inv, yr.x), 0.f);
    o.y = fmaxf(fmaf(acc.y, inv, yr.y), 0.f);
    o.z = fmaxf(fmaf(acc.z, inv, yr.z), 0.f);
    o.w = fmaxf(fmaf(acc.w, inv, yr.w), 0.f);
    *(float4*)(x2c + (size_t)task * 256 + ch * HH + j4) = o;
  }
}

// =============== layer-3 aggregate: wave-per-task, TLP-hidden gather ===============
__global__ __launch_bounds__(256) void k_agg3(const float* __restrict__ x2c,
    const ull* __restrict__ csrk, const int* __restrict__ rowptr,
    const int4* __restrict__ pack, const int* __restrict__ plist,
    const int* __restrict__ minv, int T, float* __restrict__ aggp) {
  int gt = blockIdx.x * blockDim.x + threadIdx.x;
  int w = gt >> 6, lane = gt & 63;
  int nw = (gridDim.x * blockDim.x) >> 6;
  int j4 = lane * 4;
  for (int task = w; task < T; task += nw) {
    int n = plist[task];
    int beg = rowptr[n], d = pack[n].x;
    float4 acc = make_float4(0, 0, 0, 0);
    int i = 0;
    for (; i + 4 <= d; i += 4) {
      int m0 = minv[(int)(csrk[beg + i] & 0xFFFFFFFFULL)];
      int m1 = minv[(int)(csrk[beg + i + 1] & 0xFFFFFFFFULL)];
      int m2 = minv[(int)(csrk[beg + i + 2] & 0xFFFFFFFFULL)];
      int m3 = minv[(int)(csrk[beg + i + 3] & 0xFFFFFFFFULL)];
      float4 v0 = *(const float4*)(x2c + (size_t)m0 * 256 + j4);
      float4 v1 = *(const float4*)(x2c + (size_t)m1 * 256 + j4);
      float4 v2 = *(const float4*)(x2c + (size_t)m2 * 256 + j4);
      float4 v3 = *(const float4*)(x2c + (size_t)m3 * 256 + j4);
      acc.x += v0.x + v1.x + v2.x + v3.x;
      acc.y += v0.y + v1.y + v2.y + v3.y;
      acc.z += v0.z + v1.z + v2.z + v3.z;
      acc.w += v0.w + v1.w + v2.w + v3.w;
    }
    for (; i < d; i++) {
      int m0 = minv[(int)(csrk[beg + i] & 0xFFFFFFFFULL)];
      float4 v0 = *(const float4*)(x2c + (size_t)m0 * 256 + j4);
      acc.x += v0.x; acc.y += v0.y; acc.z += v0.z; acc.w += v0.w;
    }
    float inv = 1.0f / (float)max(d, 1);
    float4 o = make_float4(acc.x * inv, acc.y * inv, acc.z * inv, acc.w * inv);
    *(float4*)(aggp + (size_t)task * 256 + j4) = o;
  }
}

// =============== dual GEMM + W0, k-tiled LDS-staged transposed weights ===============
#define G3 4
__global__ __launch_bounds__(256) void k_gemm3F(const float* __restrict__ aggp,
    const float* __restrict__ x2c, const float* __restrict__ Wl3,
    const float* __restrict__ Wr3, const float* __restrict__ W0,
    const float* __restrict__ bl2, const float* __restrict__ b0,
    const int* __restrict__ plist, const int* __restrict__ minv,
    float* __restrict__ tmp0) {
  __shared__ float aS[G3][256], xS[G3][256], x3S[G3][256];
  __shared__ float wAS[32][HH + 1], wBS[32][HH + 1];
  int t = threadIdx.x;
  int i0 = blockIdx.x * G3;
  int j = t & 127, c = t >> 7;
#pragma unroll
  for (int g = 0; g < G3; g++) {
    int i = i0 + g;
    aS[g][t] = aggp[(size_t)i * 256 + t];
    xS[g][t] = x2c[(size_t)minv[plist[i]] * 256 + t];
  }
  float acc[G3];
#pragma unroll
  for (int g = 0; g < G3; g++) acc[g] = bl2[j];
  // staging decomposition: flat f = q*1024 + t*4 -> jw = f>>5, kk = f&31
  int jw = t >> 3;            // + q*32
  int kk0 = (t & 7) * 4;
  for (int kt = 0; kt < 4; kt++) {
    __syncthreads();
#pragma unroll
    for (int q = 0; q < 4; q++) {
      int jj = q * 32 + jw;
      float4 va = *(const float4*)(Wl3 + (size_t)jj * HH + kt * 32 + kk0);
      float4 vb = *(const float4*)(Wr3 + (size_t)jj * HH + kt * 32 + kk0);
      wAS[kk0 + 0][jj] = va.x; wAS[kk0 + 1][jj] = va.y;
      wAS[kk0 + 2][jj] = va.z; wAS[kk0 + 3][jj] = va.w;
      wBS[kk0 + 0][jj] = vb.x; wBS[kk0 + 1][jj] = vb.y;
      wBS[kk0 + 2][jj] = vb.z; wBS[kk0 + 3][jj] = vb.w;
    }
    __syncthreads();
#pragma unroll
    for (int kk = 0; kk < 32; kk++) {
      int k = kt * 32 + kk;
      float wl = wAS[kk][j], wr = wBS[kk][j];
#pragma unroll
      for (int g = 0; g < G3; g++)
        acc[g] = fmaf(aS[g][c * HH + k], wl, fmaf(xS[g][c * HH + k], wr, acc[g]));
    }
  }
#pragma unroll
  for (int g = 0; g < G3; g++) x3S[g][t] = acc[g];
  float acc2[G3];
#pragma unroll
  for (int g = 0; g < G3; g++) acc2[g] = b0[j];
  for (int kt = 0; kt < 4; kt++) {
    __syncthreads();   // also covers x3S writes before first read
#pragma unroll
    for (int q = 0; q < 4; q++) {
      int jj = q * 32 + jw;
      float4 v0 = *(const float4*)(W0 + (size_t)jj * HH + kt * 32 + kk0);
      wAS[kk0 + 0][jj] = v0.x; wAS[kk0 + 1][jj] = v0.y;
      wAS[kk0 + 2][jj] = v0.z; wAS[kk0 + 3][jj] = v0.w;
    }
    __syncthreads();
#pragma unroll
    for (int kk = 0; kk < 32; kk++) {
      int k = kt * 32 + kk;
      float w0v = wAS[kk][j];
#pragma unroll
      for (int g = 0; g < G3; g++)
        acc2[g] = fmaf(x3S[g][c * HH + k], w0v, acc2[g]);
    }
  }
#pragma unroll
  for (int g = 0; g < G3; g++)
    tmp0[(size_t)(2 * (i0 + g) + c) * HH + j] = fmaxf(acc2[g], 0.f);
}

// =============== pair product + final MLP ===============
__global__ __launch_bounds__(256) void k_finalP(const float* __restrict__ tmp0,
    const float* __restrict__ W1, const float* __restrict__ b1,
    const float* __restrict__ W2, const float* __restrict__ b2,
    int P, float* __restrict__ out) {
  __shared__ float pS[2][HH];
  __shared__ float wred[4];
  int t = threadIdx.x;
  int half = t >> 7, j = t & 127;
  int i = blockIdx.x * 2 + half;
  float hs = tmp0[(size_t)(2 * i) * HH + j] + tmp0[(size_t)(2 * i + 1) * HH + j];
  float hd = tmp0[(size_t)(2 * (i + P)) * HH + j] + tmp0[(size_t)(2 * (i + P) + 1) * HH + j];
  pS[half][j] = hs * hd;
  __syncthreads();
  float acc = b1[j];
#pragma unroll 8
  for (int k = 0; k < HH; k++) acc = fmaf(pS[half][k], W1[j * HH + k], acc);
  float v = fmaxf(acc, 0.f) * W2[j];
  for (int off = 32; off > 0; off >>= 1) v += __shfl_down(v, off);
  int wid = t >> 6, lane = t & 63;
  if (lane == 0) wred[wid] = v;
  __syncthreads();
  if (t == 0) out[i] = wred[0] + wred[1] + b2[0];
  else if (t == 128) out[i] = wred[2] + wred[3] + b2[0];
}

extern "C" void kernel_launch(void* const* d_in, const int* in_sizes, int n_in,
                              void* d_out, int out_size, void* d_ws, size_t ws_size,
                              hipStream_t stream) {
  const int* z = (const int*)d_in[0];
  const int* ei = (const int*)d_in[1];
  const float* z_table = (const float*)d_in[3];
  const float* conv_Wl = (const float*)d_in[4];
  const float* conv_bl = (const float*)d_in[5];
  const float* conv_Wr = (const float*)d_in[6];
  const float* W0 = (const float*)d_in[7];
  const float* b0 = (const float*)d_in[8];
  const float* W1 = (const float*)d_in[9];
  const float* b1 = (const float*)d_in[10];
  const float* W2 = (const float*)d_in[11];
  const float* b2 = (const float*)d_in[12];
  float* out = (float*)d_out;

  int N = in_sizes[0];
  int E = in_sizes[1] / 2;
  int P = out_size;
  int P2 = 2 * P;
  const int* srcA = ei;
  const int* dstA = ei + E;

  char* basep = (char*)d_ws;
  size_t off = 0;
  auto alloc = [&](size_t bytes) -> char* {
    off = (off + 255) & ~(size_t)255;
    char* pp = basep + off; off += bytes; return pp;
  };
  float* y_l   = (float*)alloc((size_t)1024 * HH * 4);
  float* y_rb  = (float*)alloc((size_t)1024 * HH * 4);
  float* vecs  = (float*)alloc((size_t)4 * HH * 4);
  float* x2c   = (float*)alloc((size_t)N * 256 * 4);
  float* aggp  = (float*)alloc((size_t)P2 * 256 * 4);
  float* tmp0  = (float*)alloc((size_t)2 * P2 * HH * 4);
  ull*   cnt64 = (ull*)alloc((size_t)N * 8);
  int*   mark  = (int*)alloc((size_t)N * 4);
  int*   pos   = (int*)alloc((size_t)E * 4);
  int*   rowptr= (int*)alloc((size_t)N * 4);
  int*   mlist = (int*)alloc((size_t)N * 4);
  int*   minv  = (int*)alloc((size_t)N * 4);
  int*   plist = (int*)alloc((size_t)P2 * 4);
  ull*   csrk  = (ull*)alloc((size_t)E * 8);
  ull*   locout= (ull*)alloc((size_t)N * 8);
  ull*   partials = (ull*)alloc(256 * 8);
  int*   Rm_dev = (int*)alloc(256);
  u16*   keyN  = (u16*)alloc((size_t)N * 2);
  int4*  pack  = (int4*)alloc((size_t)N * 16);
  (void)ws_size; (void)n_in;

  k_ytab<<<64, 256, 0, stream>>>(z_table, conv_Wl, conv_Wr,
                                 conv_Wl + HH * HH, conv_Wr + HH * HH,
                                 conv_bl, conv_bl + HH, y_l, y_rb, vecs,
                                 z, N, cnt64, mark);
  k_edge<<<1024, 256, 0, stream>>>(z, srcA, dstA, E, cnt64, mark, pos);
  int nb = (N + 1023) / 1024;
  k_scan1<<<nb, 256, 0, stream>>>(cnt64, mark, z, N, locout, partials);
  k_post<<<(N + 255) / 256, 256, 0, stream>>>(locout, partials, z, mark, cnt64, N, P,
                                              rowptr, mlist, minv, plist, Rm_dev, pack, keyN);
  k_csrk<<<(E + 255) / 256, 256, 0, stream>>>(srcA, dstA, E, rowptr, pos, keyN, csrk);
  k_agg2Y<<<2048, 256, 0, stream>>>(pack, csrk, y_l, y_rb, vecs, conv_bl, conv_bl + HH,
                                    conv_Wl + HH * HH, conv_Wr + HH * HH,
                                    rowptr, mlist, Rm_dev, x2c);
  k_agg3<<<512, 256, 0, stream>>>(x2c, csrk, rowptr, pack, plist, minv, P2, aggp);
  k_gemm3F<<<P2 / G3, 256, 0, stream>>>(aggp, x2c, conv_Wl + 2 * HH * HH,
                                        conv_Wr + 2 * HH * HH, W0,
                                        conv_bl + 2 * HH, b0, plist, minv, tmp0);
  k_finalP<<<P / 2, 256, 0, stream>>>(tmp0, W1, b1, W2, b2, P, out);
}

// Round 7
// 128.114 us; speedup vs baseline: 5.6196x; 1.0358x over previous
//
#include <hip/hip_runtime.h>
#include <stdint.h>

#define HH 128
typedef unsigned long long ull;
typedef unsigned short u16;

__device__ __forceinline__ ull shfl_up64(ull v, int d) {
  unsigned lo = (unsigned)__shfl_up((int)(unsigned)(v & 0xffffffffULL), d);
  unsigned hi = (unsigned)__shfl_up((int)(unsigned)(v >> 32), d);
  return ((ull)hi << 32) | (ull)lo;
}
__device__ __forceinline__ ull shfl_down64(ull v, int d) {
  unsigned lo = (unsigned)__shfl_down((int)(unsigned)(v & 0xffffffffULL), d);
  unsigned hi = (unsigned)__shfl_down((int)(unsigned)(v >> 32), d);
  return ((ull)hi << 32) | (ull)lo;
}

// =============== y-tables + init prologue; all weight reads LDS-staged/coalesced ===============
__global__ __launch_bounds__(256) void k_ytab(
    const float* __restrict__ zt, const float* __restrict__ Wl0,
    const float* __restrict__ Wr0, const float* __restrict__ Wl2,
    const float* __restrict__ Wr2, const float* __restrict__ bl0,
    const float* __restrict__ bl1, float* __restrict__ y_l,
    float* __restrict__ y_rb, float* __restrict__ vecs_g,
    const int* __restrict__ z, int N, ull* __restrict__ cnt64,
    int* __restrict__ mark) {
  __shared__ float ztS[2][HH];
  __shared__ float vS[4][HH];
  __shared__ float xS[16][HH];
  __shared__ float wAS[32][HH + 1], wBS[32][HH + 1];
  int t = threadIdx.x;
  // init prologue: zero cnt64, seed mark (stream order protects k_edge)
  {
    int gid = blockIdx.x * 256 + t;
    int nthr = gridDim.x * 256;
    for (int n = gid; n < N; n += nthr) {
      cnt64[n] = 0ULL;
      mark[n] = (z[n] <= 2) ? 1 : 0;
    }
  }
  ztS[t >> 7][t & 127] = zt[t];
  __syncthreads();
  int j = t & 127, half = t >> 7;
  int jw = t >> 3, kk0 = (t & 7) * 4;
  // phase B: vecs (4 matvecs) via staged k-tiles
  float accA = 0.f, accR = 0.f;
  for (int kt = 0; kt < 4; kt++) {
    __syncthreads();
#pragma unroll
    for (int q = 0; q < 4; q++) {
      int jj = q * 32 + jw;
      float4 va = *(const float4*)(Wl0 + (size_t)jj * HH + kt * 32 + kk0);
      float4 vb = *(const float4*)(Wr0 + (size_t)jj * HH + kt * 32 + kk0);
      wAS[kk0 + 0][jj] = va.x; wAS[kk0 + 1][jj] = va.y;
      wAS[kk0 + 2][jj] = va.z; wAS[kk0 + 3][jj] = va.w;
      wBS[kk0 + 0][jj] = vb.x; wBS[kk0 + 1][jj] = vb.y;
      wBS[kk0 + 2][jj] = vb.z; wBS[kk0 + 3][jj] = vb.w;
    }
    __syncthreads();
#pragma unroll
    for (int kk = 0; kk < 32; kk++) {
      float zk = ztS[half][kt * 32 + kk];
      accA = fmaf(zk, wAS[kk][j], accA);
      accR = fmaf(zk, wBS[kk][j], accR);
    }
  }
  __syncthreads();
  vS[half][j] = accA;       // A0/A1
  vS[2 + half][j] = accR;   // R0/R1
  __syncthreads();
  if (blockIdx.x == 0) {
    vecs_g[t] = vS[t >> 7][t & 127];
    vecs_g[256 + t] = vS[2 + (t >> 7)][t & 127];
  }
  // phase C: 16 x1-variant rows for this block
  int v0 = blockIdx.x * 16;
#pragma unroll
  for (int rep = 0; rep < 8; rep++) {
    int idx = t + rep * 256;
    int r = idx >> 7, jx = idx & 127;
    int v = v0 + r;
    int d = v >> 4, cnt = (v >> 1) & 7, sel = v & 1;
    float invd = 1.0f / (float)max(d, 1);
    float u1 = (float)cnt * invd, u0 = (float)(d - cnt) * invd;
    xS[r][jx] = fmaxf(fmaf(u0, vS[0][jx], fmaf(u1, vS[1][jx], bl0[jx] + vS[2 + sel][jx])), 0.f);
  }
  // phase D: dual GEMM (16 rows x 128) with staged Wl2/Wr2 k-tiles
  int rh = t >> 7;
  float al[8], ar[8];
#pragma unroll
  for (int q = 0; q < 8; q++) { al[q] = 0.f; ar[q] = 0.f; }
  for (int kt = 0; kt < 4; kt++) {
    __syncthreads();   // covers xS writes (first iter) + prior wAS/wBS reads
#pragma unroll
    for (int q = 0; q < 4; q++) {
      int jj = q * 32 + jw;
      float4 va = *(const float4*)(Wl2 + (size_t)jj * HH + kt * 32 + kk0);
      float4 vb = *(const float4*)(Wr2 + (size_t)jj * HH + kt * 32 + kk0);
      wAS[kk0 + 0][jj] = va.x; wAS[kk0 + 1][jj] = va.y;
      wAS[kk0 + 2][jj] = va.z; wAS[kk0 + 3][jj] = va.w;
      wBS[kk0 + 0][jj] = vb.x; wBS[kk0 + 1][jj] = vb.y;
      wBS[kk0 + 2][jj] = vb.z; wBS[kk0 + 3][jj] = vb.w;
    }
    __syncthreads();
#pragma unroll
    for (int kk = 0; kk < 32; kk++) {
      float wl = wAS[kk][j], wr = wBS[kk][j];
#pragma unroll
      for (int q = 0; q < 8; q++) {
        float x = xS[rh * 8 + q][kt * 32 + kk];
        al[q] = fmaf(x, wl, al[q]);
        ar[q] = fmaf(x, wr, ar[q]);
      }
    }
  }
  float bb = bl1[j];
#pragma unroll
  for (int q = 0; q < 8; q++) {
    int v = v0 + rh * 8 + q;
    y_l[((size_t)v << 7) + j] = al[q];
    y_rb[((size_t)v << 7) + j] = ar[q] + bb;
  }
}

// =============== edge pass: packed atomic gives slot for free ===============
__global__ void k_edge(const int* __restrict__ z, const int* __restrict__ src,
                       const int* __restrict__ dst, int E,
                       ull* __restrict__ cnt64, int* __restrict__ mark,
                       int* __restrict__ pos) {
  int tid = blockIdx.x * blockDim.x + threadIdx.x;
  int stride = gridDim.x * blockDim.x;
  for (int e = tid; e < E; e += stride) {
    int s = src[e], d = dst[e];
    int zs = z[s];
    ull val = 1ULL | ((ull)(zs == 1) << 20) | ((ull)(zs == 2) << 40);
    ull old = atomicAdd(&cnt64[d], val);
    pos[e] = (int)(old & 0xFFFFF);
    if (z[d] <= 2) mark[s] = 1;
  }
}

// ---- packed 64-bit scan: deg(0..19) | mark(20..39) | z==1(40..51) | z==2(52..63) ----
__global__ void k_scan1(const ull* __restrict__ cnt64, const int* __restrict__ mark,
                        const int* __restrict__ z, int N,
                        ull* __restrict__ locout, ull* __restrict__ partials) {
  __shared__ ull wsum[4];
  int t = threadIdx.x, b = blockIdx.x;
  int base = b * 1024 + t * 4;
  ull l[4]; ull s = 0;
  for (int i = 0; i < 4; i++) {
    int idx = base + i; ull v = 0;
    if (idx < N) {
      int zz = z[idx];
      v = (cnt64[idx] & 0xFFFFFULL) | ((ull)mark[idx] << 20)
        | ((ull)(zz == 1) << 40) | ((ull)(zz == 2) << 52);
    }
    l[i] = s; s += v;
  }
  int lane = t & 63, wid = t >> 6;
  ull vi = s;
  for (int d2 = 1; d2 < 64; d2 <<= 1) { ull o = shfl_up64(vi, d2); if (lane >= d2) vi += o; }
  if (lane == 63) wsum[wid] = vi;
  __syncthreads();
  ull woff = 0;
  for (int w = 0; w < wid; w++) woff += wsum[w];
  ull thrbase = woff + vi - s;
  for (int i = 0; i < 4; i++) {
    int idx = base + i;
    if (idx < N) locout[idx] = thrbase + l[i];
  }
  if (t == 255) partials[b] = woff + vi;
}

// ---- consume scan: rowptr, mlist/minv, plist, pack, keyN ----
__global__ __launch_bounds__(256) void k_post(const ull* __restrict__ locout, const ull* __restrict__ partials,
                       const int* __restrict__ z, const int* __restrict__ mark,
                       const ull* __restrict__ cnt64,
                       int N, int P, int* __restrict__ rowptr, int* __restrict__ mlist,
                       int* __restrict__ minv, int* __restrict__ plist,
                       int* __restrict__ Rm, int4* __restrict__ pack,
                       u16* __restrict__ keyN) {
  __shared__ ull base_s;
  int t = threadIdx.x;
  if (t < 64) {
    int need = blockIdx.x >> 2;
    ull v = (t < need) ? partials[t] : 0ULL;
    for (int o = 32; o > 0; o >>= 1) v += shfl_down64(v, o);
    if (t == 0) base_s = v;
  }
  __syncthreads();
  int n = blockIdx.x * 256 + t;
  if (n >= N) return;
  ull s = locout[n] + base_s;
  int rp = (int)(s & 0xFFFFF);
  int mp = (int)((s >> 20) & 0xFFFFF);
  int r1 = (int)((s >> 40) & 0xFFF);
  int r2 = (int)(s >> 52);
  rowptr[n] = rp;
  int mk = mark[n];
  if (mk) { mlist[mp] = n; minv[n] = mp; }
  int zz = z[n];
  if (zz == 1) plist[r1] = n;
  else if (zz == 2) plist[P + r2] = n;
  ull cv = cnt64[n];
  int dd = (int)(cv & 0xFFFFF), c1 = (int)((cv >> 20) & 0xFFFFF), c2 = (int)((cv >> 40) & 0xFFFFF);
  pack[n] = make_int4(dd, c1, c2, zz);
  int wcls = (zz == 1) ? 1 : ((zz == 2) ? 2 : 0);
  u16 key;
  if (dd < 64 && c1 < 8 && c2 < 8) key = (u16)(dd | (c1 << 6) | (c2 << 9) | (wcls << 12));
  else key = 0x8000;
  keyN[n] = key;
  if (n == N - 1) *Rm = mp + mk;
}

// ---- CSR fill: pure scatter, only for marked dsts (others never read) ----
__global__ void k_csrk(const int* __restrict__ src, const int* __restrict__ dst, int E,
                       const int* __restrict__ rowptr, const int* __restrict__ pos,
                       const u16* __restrict__ keyN, const int* __restrict__ mark,
                       ull* __restrict__ csrk) {
  int e = blockIdx.x * blockDim.x + threadIdx.x;
  if (e >= E) return;
  int d = dst[e];
  if (!mark[d]) return;
  int s = src[e];
  csrk[rowptr[d] + pos[e]] = (ull)(unsigned)s | ((ull)keyN[s] << 32);
}

// ---- exact fallback (deg>=64 or cnt>=8): on-the-fly matvec, raw weights ----
__device__ __noinline__ float4 yrow_fb(const float* __restrict__ vecs,
    const float* __restrict__ bl0, const float* __restrict__ Wm,
    int j4, int d, int cnt, int sel) {
  float invd = 1.0f / (float)max(d, 1);
  float u1 = (float)cnt * invd, u0 = (float)(d - cnt) * invd;
  const float* Rv = vecs + (2 + sel) * HH;
  float4 acc = make_float4(0, 0, 0, 0);
  for (int k = 0; k < HH; k++) {
    float x = fmaxf(fmaf(u0, vecs[k], fmaf(u1, vecs[HH + k], bl0[k] + Rv[k])), 0.f);
    acc.x = fmaf(x, Wm[(j4 + 0) * HH + k], acc.x);
    acc.y = fmaf(x, Wm[(j4 + 1) * HH + k], acc.y);
    acc.z = fmaf(x, Wm[(j4 + 2) * HH + k], acc.z);
    acc.w = fmaf(x, Wm[(j4 + 3) * HH + k], acc.w);
  }
  return acc;
}

__device__ __forceinline__ float4 yl_fetch(ull cv, int ch, int chsel, int j4,
    const float* __restrict__ y_l, const int4* __restrict__ pack,
    const float* __restrict__ vecs, const float* __restrict__ bl0,
    const float* __restrict__ Wl2) {
  int key = (int)(cv >> 32);
  if (key & 0x8000) {
    int s = (int)(cv & 0xFFFFFFFFULL);
    int4 p = pack[s];
    int cc = ch ? p.z : p.y;
    int sel = (p.w == chsel) ? 1 : 0;
    return yrow_fb(vecs, bl0, Wl2, j4, p.x, cc, sel);
  }
  int cc = (key >> (6 + 3 * ch)) & 7;
  int sel = (((key >> 12) & 3) == chsel) ? 1 : 0;
  int row = ((key & 63) << 4) + (cc << 1) + sel;
  return *(const float4*)(y_l + ((size_t)row << 7) + j4);
}

// =============== layer-2: x2c[task] = relu(mean_s y_l[key(s)] + y_rb[key(n)]) ===============
__global__ __launch_bounds__(256) void k_agg2Y(const int4* __restrict__ pack,
    const ull* __restrict__ csrk, const float* __restrict__ y_l,
    const float* __restrict__ y_rb, const float* __restrict__ vecs,
    const float* __restrict__ bl0, const float* __restrict__ bl1,
    const float* __restrict__ Wl2, const float* __restrict__ Wr2,
    const int* __restrict__ rowptr, const int* __restrict__ mlist,
    const int* __restrict__ Rdev, float* __restrict__ x2c) {
  int gt = blockIdx.x * blockDim.x + threadIdx.x;
  int w = gt >> 6, lane = gt & 63;
  int nw = (gridDim.x * blockDim.x) >> 6;
  int T = *Rdev;
  int ch = lane >> 5, j4 = (lane & 31) * 4;
  int chsel = ch + 1;
  for (int task = w; task < T; task += nw) {
    int n = mlist[task];
    int4 pn = pack[n];
    int beg = rowptr[n], d = pn.x;
    float4 acc = make_float4(0, 0, 0, 0);
    int i = 0;
    for (; i + 4 <= d; i += 4) {
      ull c0 = csrk[beg + i], c1 = csrk[beg + i + 1];
      ull c2 = csrk[beg + i + 2], c3 = csrk[beg + i + 3];
      float4 v0 = yl_fetch(c0, ch, chsel, j4, y_l, pack, vecs, bl0, Wl2);
      float4 v1 = yl_fetch(c1, ch, chsel, j4, y_l, pack, vecs, bl0, Wl2);
      float4 v2 = yl_fetch(c2, ch, chsel, j4, y_l, pack, vecs, bl0, Wl2);
      float4 v3 = yl_fetch(c3, ch, chsel, j4, y_l, pack, vecs, bl0, Wl2);
      acc.x += v0.x + v1.x + v2.x + v3.x;
      acc.y += v0.y + v1.y + v2.y + v3.y;
      acc.z += v0.z + v1.z + v2.z + v3.z;
      acc.w += v0.w + v1.w + v2.w + v3.w;
    }
    for (; i < d; i++) {
      float4 v0 = yl_fetch(csrk[beg + i], ch, chsel, j4, y_l, pack, vecs, bl0, Wl2);
      acc.x += v0.x; acc.y += v0.y; acc.z += v0.z; acc.w += v0.w;
    }
    float inv = 1.0f / (float)max(d, 1);
    int ccn = ch ? pn.z : pn.y;
    int seln = (pn.w == chsel) ? 1 : 0;
    float4 yr;
    if (pn.x < 64 && ccn < 8) {
      yr = *(const float4*)(y_rb + ((size_t)(((pn.x << 3) + ccn) * 2 + seln) << 7) + j4);
    } else {
      yr = yrow_fb(vecs, bl0, Wr2, j4, pn.x, ccn, seln);
      yr.x += bl1[j4]; yr.y += bl1[j4 + 1]; yr.z += bl1[j4 + 2]; yr.w += bl1[j4 + 3];
    }
    float4 o;
    o.x = fmaxf(fmaf(acc.x, inv, yr.x), 0.f);
    o.y = fmaxf(fmaf(acc.y, inv, yr.y), 0.f);
    o.z = fmaxf(fmaf(acc.z, inv, yr.z), 0.f);
    o.w = fmaxf(fmaf(acc.w, inv, yr.w), 0.f);
    *(float4*)(x2c + (size_t)task * 256 + ch * HH + j4) = o;
  }
}

// =============== layer-3 aggregate: wave-per-task, TLP-hidden gather ===============
__global__ __launch_bounds__(256) void k_agg3(const float* __restrict__ x2c,
    const ull* __restrict__ csrk, const int* __restrict__ rowptr,
    const int4* __restrict__ pack, const int* __restrict__ plist,
    const int* __restrict__ minv, int T, float* __restrict__ aggp) {
  int gt = blockIdx.x * blockDim.x + threadIdx.x;
  int w = gt >> 6, lane = gt & 63;
  int nw = (gridDim.x * blockDim.x) >> 6;
  int j4 = lane * 4;
  for (int task = w; task < T; task += nw) {
    int n = plist[task];
    int beg = rowptr[n], d = pack[n].x;
    float4 acc = make_float4(0, 0, 0, 0);
    int i = 0;
    for (; i + 4 <= d; i += 4) {
      int m0 = minv[(int)(csrk[beg + i] & 0xFFFFFFFFULL)];
      int m1 = minv[(int)(csrk[beg + i + 1] & 0xFFFFFFFFULL)];
      int m2 = minv[(int)(csrk[beg + i + 2] & 0xFFFFFFFFULL)];
      int m3 = minv[(int)(csrk[beg + i + 3] & 0xFFFFFFFFULL)];
      float4 v0 = *(const float4*)(x2c + (size_t)m0 * 256 + j4);
      float4 v1 = *(const float4*)(x2c + (size_t)m1 * 256 + j4);
      float4 v2 = *(const float4*)(x2c + (size_t)m2 * 256 + j4);
      float4 v3 = *(const float4*)(x2c + (size_t)m3 * 256 + j4);
      acc.x += v0.x + v1.x + v2.x + v3.x;
      acc.y += v0.y + v1.y + v2.y + v3.y;
      acc.z += v0.z + v1.z + v2.z + v3.z;
      acc.w += v0.w + v1.w + v2.w + v3.w;
    }
    for (; i < d; i++) {
      int m0 = minv[(int)(csrk[beg + i] & 0xFFFFFFFFULL)];
      float4 v0 = *(const float4*)(x2c + (size_t)m0 * 256 + j4);
      acc.x += v0.x; acc.y += v0.y; acc.z += v0.z; acc.w += v0.w;
    }
    float inv = 1.0f / (float)max(d, 1);
    float4 o = make_float4(acc.x * inv, acc.y * inv, acc.z * inv, acc.w * inv);
    *(float4*)(aggp + (size_t)task * 256 + j4) = o;
  }
}

// =============== dual GEMM + W0, k-tiled LDS-staged transposed weights ===============
#define G3 4
__global__ __launch_bounds__(256) void k_gemm3F(const float* __restrict__ aggp,
    const float* __restrict__ x2c, const float* __restrict__ Wl3,
    const float* __restrict__ Wr3, const float* __restrict__ W0,
    const float* __restrict__ bl2, const float* __restrict__ b0,
    const int* __restrict__ plist, const int* __restrict__ minv,
    float* __restrict__ tmp0) {
  __shared__ float aS[G3][256], xS[G3][256], x3S[G3][256];
  __shared__ float wAS[32][HH + 1], wBS[32][HH + 1];
  int t = threadIdx.x;
  int i0 = blockIdx.x * G3;
  int j = t & 127, c = t >> 7;
#pragma unroll
  for (int g = 0; g < G3; g++) {
    int i = i0 + g;
    aS[g][t] = aggp[(size_t)i * 256 + t];
    xS[g][t] = x2c[(size_t)minv[plist[i]] * 256 + t];
  }
  float acc[G3];
#pragma unroll
  for (int g = 0; g < G3; g++) acc[g] = bl2[j];
  int jw = t >> 3;
  int kk0 = (t & 7) * 4;
  for (int kt = 0; kt < 4; kt++) {
    __syncthreads();
#pragma unroll
    for (int q = 0; q < 4; q++) {
      int jj = q * 32 + jw;
      float4 va = *(const float4*)(Wl3 + (size_t)jj * HH + kt * 32 + kk0);
      float4 vb = *(const float4*)(Wr3 + (size_t)jj * HH + kt * 32 + kk0);
      wAS[kk0 + 0][jj] = va.x; wAS[kk0 + 1][jj] = va.y;
      wAS[kk0 + 2][jj] = va.z; wAS[kk0 + 3][jj] = va.w;
      wBS[kk0 + 0][jj] = vb.x; wBS[kk0 + 1][jj] = vb.y;
      wBS[kk0 + 2][jj] = vb.z; wBS[kk0 + 3][jj] = vb.w;
    }
    __syncthreads();
#pragma unroll
    for (int kk = 0; kk < 32; kk++) {
      int k = kt * 32 + kk;
      float wl = wAS[kk][j], wr = wBS[kk][j];
#pragma unroll
      for (int g = 0; g < G3; g++)
        acc[g] = fmaf(aS[g][c * HH + k], wl, fmaf(xS[g][c * HH + k], wr, acc[g]));
    }
  }
#pragma unroll
  for (int g = 0; g < G3; g++) x3S[g][t] = acc[g];
  float acc2[G3];
#pragma unroll
  for (int g = 0; g < G3; g++) acc2[g] = b0[j];
  for (int kt = 0; kt < 4; kt++) {
    __syncthreads();   // also covers x3S writes before first read
#pragma unroll
    for (int q = 0; q < 4; q++) {
      int jj = q * 32 + jw;
      float4 v0 = *(const float4*)(W0 + (size_t)jj * HH + kt * 32 + kk0);
      wAS[kk0 + 0][jj] = v0.x; wAS[kk0 + 1][jj] = v0.y;
      wAS[kk0 + 2][jj] = v0.z; wAS[kk0 + 3][jj] = v0.w;
    }
    __syncthreads();
#pragma unroll
    for (int kk = 0; kk < 32; kk++) {
      int k = kt * 32 + kk;
      float w0v = wAS[kk][j];
#pragma unroll
      for (int g = 0; g < G3; g++)
        acc2[g] = fmaf(x3S[g][c * HH + k], w0v, acc2[g]);
    }
  }
#pragma unroll
  for (int g = 0; g < G3; g++)
    tmp0[(size_t)(2 * (i0 + g) + c) * HH + j] = fmaxf(acc2[g], 0.f);
}

// =============== pair product + final MLP (W1 LDS-staged) ===============
__global__ __launch_bounds__(256) void k_finalP(const float* __restrict__ tmp0,
    const float* __restrict__ W1, const float* __restrict__ b1,
    const float* __restrict__ W2, const float* __restrict__ b2,
    int P, float* __restrict__ out) {
  __shared__ float pS[2][HH];
  __shared__ float wAS[32][HH + 1];
  __shared__ float wred[4];
  int t = threadIdx.x;
  int half = t >> 7, j = t & 127;
  int i = blockIdx.x * 2 + half;
  float hs = tmp0[(size_t)(2 * i) * HH + j] + tmp0[(size_t)(2 * i + 1) * HH + j];
  float hd = tmp0[(size_t)(2 * (i + P)) * HH + j] + tmp0[(size_t)(2 * (i + P) + 1) * HH + j];
  pS[half][j] = hs * hd;
  int jw = t >> 3, kk0 = (t & 7) * 4;
  float acc = b1[j];
  for (int kt = 0; kt < 4; kt++) {
    __syncthreads();   // covers pS writes (first iter) + prior wAS reads
#pragma unroll
    for (int q = 0; q < 4; q++) {
      int jj = q * 32 + jw;
      float4 v = *(const float4*)(W1 + (size_t)jj * HH + kt * 32 + kk0);
      wAS[kk0 + 0][jj] = v.x; wAS[kk0 + 1][jj] = v.y;
      wAS[kk0 + 2][jj] = v.z; wAS[kk0 + 3][jj] = v.w;
    }
    __syncthreads();
#pragma unroll
    for (int kk = 0; kk < 32; kk++)
      acc = fmaf(pS[half][kt * 32 + kk], wAS[kk][j], acc);
  }
  float v = fmaxf(acc, 0.f) * W2[j];
  for (int off = 32; off > 0; off >>= 1) v += __shfl_down(v, off);
  int wid = t >> 6, lane = t & 63;
  if (lane == 0) wred[wid] = v;
  __syncthreads();
  if (t == 0) out[i] = wred[0] + wred[1] + b2[0];
  else if (t == 128) out[i] = wred[2] + wred[3] + b2[0];
}

extern "C" void kernel_launch(void* const* d_in, const int* in_sizes, int n_in,
                              void* d_out, int out_size, void* d_ws, size_t ws_size,
                              hipStream_t stream) {
  const int* z = (const int*)d_in[0];
  const int* ei = (const int*)d_in[1];
  const float* z_table = (const float*)d_in[3];
  const float* conv_Wl = (const float*)d_in[4];
  const float* conv_bl = (const float*)d_in[5];
  const float* conv_Wr = (const float*)d_in[6];
  const float* W0 = (const float*)d_in[7];
  const float* b0 = (const float*)d_in[8];
  const float* W1 = (const float*)d_in[9];
  const float* b1 = (const float*)d_in[10];
  const float* W2 = (const float*)d_in[11];
  const float* b2 = (const float*)d_in[12];
  float* out = (float*)d_out;

  int N = in_sizes[0];
  int E = in_sizes[1] / 2;
  int P = out_size;
  int P2 = 2 * P;
  const int* srcA = ei;
  const int* dstA = ei + E;

  char* basep = (char*)d_ws;
  size_t off = 0;
  auto alloc = [&](size_t bytes) -> char* {
    off = (off + 255) & ~(size_t)255;
    char* pp = basep + off; off += bytes; return pp;
  };
  float* y_l   = (float*)alloc((size_t)1024 * HH * 4);
  float* y_rb  = (float*)alloc((size_t)1024 * HH * 4);
  float* vecs  = (float*)alloc((size_t)4 * HH * 4);
  float* x2c   = (float*)alloc((size_t)N * 256 * 4);
  float* aggp  = (float*)alloc((size_t)P2 * 256 * 4);
  float* tmp0  = (float*)alloc((size_t)2 * P2 * HH * 4);
  ull*   cnt64 = (ull*)alloc((size_t)N * 8);
  int*   mark  = (int*)alloc((size_t)N * 4);
  int*   pos   = (int*)alloc((size_t)E * 4);
  int*   rowptr= (int*)alloc((size_t)N * 4);
  int*   mlist = (int*)alloc((size_t)N * 4);
  int*   minv  = (int*)alloc((size_t)N * 4);
  int*   plist = (int*)alloc((size_t)P2 * 4);
  ull*   csrk  = (ull*)alloc((size_t)E * 8);
  ull*   locout= (ull*)alloc((size_t)N * 8);
  ull*   partials = (ull*)alloc(256 * 8);
  int*   Rm_dev = (int*)alloc(256);
  u16*   keyN  = (u16*)alloc((size_t)N * 2);
  int4*  pack  = (int4*)alloc((size_t)N * 16);
  (void)ws_size; (void)n_in;

  k_ytab<<<64, 256, 0, stream>>>(z_table, conv_Wl, conv_Wr,
                                 conv_Wl + HH * HH, conv_Wr + HH * HH,
                                 conv_bl, conv_bl + HH, y_l, y_rb, vecs,
                                 z, N, cnt64, mark);
  k_edge<<<1024, 256, 0, stream>>>(z, srcA, dstA, E, cnt64, mark, pos);
  int nb = (N + 1023) / 1024;
  k_scan1<<<nb, 256, 0, stream>>>(cnt64, mark, z, N, locout, partials);
  k_post<<<(N + 255) / 256, 256, 0, stream>>>(locout, partials, z, mark, cnt64, N, P,
                                              rowptr, mlist, minv, plist, Rm_dev, pack, keyN);
  k_csrk<<<(E + 255) / 256, 256, 0, stream>>>(srcA, dstA, E, rowptr, pos, keyN, mark, csrk);
  k_agg2Y<<<2048, 256, 0, stream>>>(pack, csrk, y_l, y_rb, vecs, conv_bl, conv_bl + HH,
                                    conv_Wl + HH * HH, conv_Wr + HH * HH,
                                    rowptr, mlist, Rm_dev, x2c);
  k_agg3<<<512, 256, 0, stream>>>(x2c, csrk, rowptr, pack, plist, minv, P2, aggp);
  k_gemm3F<<<P2 / G3, 256, 0, stream>>>(aggp, x2c, conv_Wl + 2 * HH * HH,
                                        conv_Wr + 2 * HH * HH, W0,
                                        conv_bl + 2 * HH, b0, plist, minv, tmp0);
  k_finalP<<<P / 2, 256, 0, stream>>>(tmp0, W1, b1, W2, b2, P, out);
}